// Round 1
// baseline (556.240 us; speedup 1.0000x reference)
//
#include <hip/hip_runtime.h>
#include <hip/hip_bf16.h>

typedef unsigned short u16;
typedef __attribute__((ext_vector_type(8))) short bfrag;   // 8 bf16 = 4 VGPR (MFMA A/B frag)
typedef __attribute__((ext_vector_type(4))) float f32x4;   // MFMA C/D frag
typedef __attribute__((ext_vector_type(8))) unsigned short us8;
typedef __attribute__((ext_vector_type(4))) unsigned short us4;

__device__ __forceinline__ u16 f2bf(float f) {
  union { float f; unsigned int u; } x; x.f = f;
  unsigned int r = x.u + 0x7fffu + ((x.u >> 16) & 1u);
  return (u16)(r >> 16);
}
__device__ __forceinline__ float bf2f(u16 u) {
  union { unsigned int u; float f; } x; x.u = ((unsigned int)u) << 16;
  return x.f;
}

__device__ __forceinline__ void gld16(const void* g, void* l) {
  __builtin_amdgcn_global_load_lds((const __attribute__((address_space(1))) void*)g,
                                   (__attribute__((address_space(3))) void*)l, 16, 0, 0);
}

// ---------------------------------------------------------------------------
// Kernel 0: transpose + convert weights: W[k][n] f32 (1024x1024) -> Wt[n][k] bf16
// ---------------------------------------------------------------------------
__global__ __launch_bounds__(256) void transpose_w(const float* __restrict__ W0,
                                                   const float* __restrict__ W1,
                                                   const float* __restrict__ W2,
                                                   u16* __restrict__ T0,
                                                   u16* __restrict__ T1,
                                                   u16* __restrict__ T2) {
  const float* W = (blockIdx.z == 0) ? W0 : ((blockIdx.z == 1) ? W1 : W2);
  u16* T = (blockIdx.z == 0) ? T0 : ((blockIdx.z == 1) ? T1 : T2);
  __shared__ u16 tile[64][72];   // [k-local][n-local], padded
  const int t = threadIdx.x;
  const int rr = t >> 4;          // 0..15
  const int cc = (t & 15) * 4;    // 0..60
  const int kbase = blockIdx.y * 64, nbase = blockIdx.x * 64;
#pragma unroll
  for (int j = 0; j < 4; ++j) {
    int kl = rr + j * 16;
    float4 v = *(const float4*)(W + (size_t)(kbase + kl) * 1024 + nbase + cc);
    tile[kl][cc + 0] = f2bf(v.x);
    tile[kl][cc + 1] = f2bf(v.y);
    tile[kl][cc + 2] = f2bf(v.z);
    tile[kl][cc + 3] = f2bf(v.w);
  }
  __syncthreads();
#pragma unroll
  for (int j = 0; j < 4; ++j) {
    int nl = rr + j * 16;
    us4 o;
    o[0] = tile[cc + 0][nl];
    o[1] = tile[cc + 1][nl];
    o[2] = tile[cc + 2][nl];
    o[3] = tile[cc + 3][nl];
    *(us4*)(T + (size_t)(nbase + nl) * 1024 + kbase + cc) = o;
  }
}

// ---------------------------------------------------------------------------
// Kernel 1: projection GEMM. out(bf16) = A(f32, Rx1024) @ Wt^T + bias
//   Wt is bf16 [n][k] (pre-transposed).  TR=true writes lvt[b][o][m] layout.
//   Grid: (8 col-tiles, 128 row-tiles). Block 256 (4 waves, 2x2).
// ---------------------------------------------------------------------------
template <bool TR>
__global__ __launch_bounds__(256) void gemm_proj(const float* __restrict__ A,
                                                 const u16* __restrict__ Wt,
                                                 const float* __restrict__ bias,
                                                 u16* __restrict__ out) {
  const int br = blockIdx.y, bc = blockIdx.x;
  const int tid = threadIdx.x, w = tid >> 6;
  const int l = tid & 63, fr = l & 15, fq = l >> 4;
  const int wm = w >> 1, wn = w & 1;

  __shared__ __align__(16) u16 Ab[128 * 32];
  __shared__ __align__(16) u16 Bb[128 * 32];

  f32x4 acc[4][4] = {};

  const int arow = tid >> 2, aseg = tid & 3;   // A staging: 8 f32 per thread per half

  for (int k0 = 0; k0 < 1024; k0 += 32) {
    // ---- stage A: f32 -> bf16, reg-staged, lane-contiguous ds_write (conflict-free)
#pragma unroll
    for (int hh = 0; hh < 2; ++hh) {
      int r = arow + hh * 64;
      const float* g = A + (size_t)(br * 128 + r) * 1024 + k0 + aseg * 8;
      float4 v0 = *(const float4*)g;
      float4 v1 = *(const float4*)(g + 4);
      us8 pk;
      pk[0] = f2bf(v0.x); pk[1] = f2bf(v0.y); pk[2] = f2bf(v0.z); pk[3] = f2bf(v0.w);
      pk[4] = f2bf(v1.x); pk[5] = f2bf(v1.y); pk[6] = f2bf(v1.z); pk[7] = f2bf(v1.w);
      *(us8*)(Ab + r * 32 + aseg * 8) = pk;
    }
    // ---- stage Wt tile via global_load_lds (bf16, k-contiguous rows)
#pragma unroll
    for (int i = 0; i < 2; ++i) {
      int li = i * 256 + tid;
      int row = li >> 2, seg = li & 3;
      gld16(Wt + (size_t)(bc * 128 + row) * 1024 + k0 + seg * 8,
            Bb + (size_t)(i * 256 + w * 64) * 8);
    }
    __syncthreads();
    bfrag a[4], b[4];
#pragma unroll
    for (int m = 0; m < 4; ++m)
      a[m] = *(const bfrag*)(Ab + (wm * 64 + m * 16 + fr) * 32 + fq * 8);
#pragma unroll
    for (int n = 0; n < 4; ++n)
      b[n] = *(const bfrag*)(Bb + (wn * 64 + n * 16 + fr) * 32 + fq * 8);
#pragma unroll
    for (int m = 0; m < 4; ++m)
#pragma unroll
      for (int n = 0; n < 4; ++n)
        acc[m][n] = __builtin_amdgcn_mfma_f32_16x16x32_bf16(a[m], b[n], acc[m][n], 0, 0, 0);
    __syncthreads();
  }

#pragma unroll
  for (int m = 0; m < 4; ++m) {
    int r0 = br * 128 + wm * 64 + m * 16 + fq * 4;
#pragma unroll
    for (int n = 0; n < 4; ++n) {
      int c = bc * 128 + wn * 64 + n * 16 + fr;
      float bc_ = bias[c];
      f32x4 vv = acc[m][n];
      if (TR) {
        // out is lvt[b][o=c][m-pos]: b = r0>>11, m-pos = r0&2047 (4 consecutive)
        int bb = r0 >> 11, mm = r0 & 2047;
        us4 o;
        o[0] = f2bf(vv[0] + bc_);
        o[1] = f2bf(vv[1] + bc_);
        o[2] = f2bf(vv[2] + bc_);
        o[3] = f2bf(vv[3] + bc_);
        *(us4*)(out + ((size_t)bb * 1024 + c) * 2048 + mm) = o;
      } else {
#pragma unroll
        for (int j = 0; j < 4; ++j)
          out[(size_t)(r0 + j) * 1024 + c] = f2bf(vv[j] + bc_);
      }
    }
  }
}

// ---------------------------------------------------------------------------
// Kernel 2: scores = (lq @ lk^T) / 32, bf16 out. Per-batch (grid.z).
// ---------------------------------------------------------------------------
__global__ __launch_bounds__(256) void gemm_scores(const u16* __restrict__ lq,
                                                   const u16* __restrict__ lk,
                                                   u16* __restrict__ probs) {
  const int z = blockIdx.z;
  const u16* A = lq + (size_t)z * 2048 * 1024;
  const u16* Bt = lk + (size_t)z * 2048 * 1024;
  u16* C = probs + (size_t)z * 2048 * 2048;
  const int br = blockIdx.y, bc = blockIdx.x;
  const int tid = threadIdx.x, w = tid >> 6;
  const int l = tid & 63, fr = l & 15, fq = l >> 4;
  const int wm = w >> 1, wn = w & 1;

  __shared__ __align__(16) u16 Ab[128 * 32];
  __shared__ __align__(16) u16 Bb[128 * 32];

  f32x4 acc[4][4] = {};

  for (int k0 = 0; k0 < 1024; k0 += 32) {
#pragma unroll
    for (int i = 0; i < 2; ++i) {
      int li = i * 256 + tid;
      int row = li >> 2, seg = li & 3;
      gld16(A + (size_t)(br * 128 + row) * 1024 + k0 + seg * 8,
            Ab + (size_t)(i * 256 + w * 64) * 8);
      gld16(Bt + (size_t)(bc * 128 + row) * 1024 + k0 + seg * 8,
            Bb + (size_t)(i * 256 + w * 64) * 8);
    }
    __syncthreads();
    bfrag a[4], b[4];
#pragma unroll
    for (int m = 0; m < 4; ++m)
      a[m] = *(const bfrag*)(Ab + (wm * 64 + m * 16 + fr) * 32 + fq * 8);
#pragma unroll
    for (int n = 0; n < 4; ++n)
      b[n] = *(const bfrag*)(Bb + (wn * 64 + n * 16 + fr) * 32 + fq * 8);
#pragma unroll
    for (int m = 0; m < 4; ++m)
#pragma unroll
      for (int n = 0; n < 4; ++n)
        acc[m][n] = __builtin_amdgcn_mfma_f32_16x16x32_bf16(a[m], b[n], acc[m][n], 0, 0, 0);
    __syncthreads();
  }

#pragma unroll
  for (int m = 0; m < 4; ++m) {
    int r0 = br * 128 + wm * 64 + m * 16 + fq * 4;
#pragma unroll
    for (int n = 0; n < 4; ++n) {
      int c = bc * 128 + wn * 64 + n * 16 + fr;
      f32x4 vv = acc[m][n];
#pragma unroll
      for (int j = 0; j < 4; ++j)
        C[(size_t)(r0 + j) * 2048 + c] = f2bf(vv[j] * 0.03125f);
    }
  }
}

// ---------------------------------------------------------------------------
// Kernel 3: masked softmax over m, in place on probs (bf16). One block per row.
// ---------------------------------------------------------------------------
__global__ __launch_bounds__(256) void softmax_mask(u16* __restrict__ probs,
                                                    const int* __restrict__ seq) {
  const int bid = blockIdx.x;
  const int b = bid >> 11, n = bid & 2047;
  const int len = seq[b];
  u16* row = probs + ((size_t)b * 2048 + n) * 2048;
  const int t = threadIdx.x;
  const int w = t >> 6, l = t & 63;

  us8 sv = *(const us8*)(row + t * 8);
  float vals[8];
  float vmax = -1e30f;
#pragma unroll
  for (int e = 0; e < 8; ++e) {
    int m = t * 8 + e;
    float x = bf2f(sv[e]);
    vals[e] = (m < len) ? x : -1e30f;
    vmax = fmaxf(vmax, vals[e]);
  }
#pragma unroll
  for (int o = 32; o > 0; o >>= 1) vmax = fmaxf(vmax, __shfl_xor(vmax, o, 64));
  __shared__ float sm[4], ss[4];
  if (l == 0) sm[w] = vmax;
  __syncthreads();
  vmax = fmaxf(fmaxf(sm[0], sm[1]), fmaxf(sm[2], sm[3]));

  float ev[8];
  float sum = 0.f;
#pragma unroll
  for (int e = 0; e < 8; ++e) {
    int m = t * 8 + e;
    float p = (m < len) ? __expf(vals[e] - vmax) : 0.f;
    ev[e] = p;
    sum += p;
  }
#pragma unroll
  for (int o = 32; o > 0; o >>= 1) sum += __shfl_xor(sum, o, 64);
  if (l == 0) ss[w] = sum;
  __syncthreads();
  sum = ss[0] + ss[1] + ss[2] + ss[3];
  float inv = 1.f / sum;
  us8 ov;
#pragma unroll
  for (int e = 0; e < 8; ++e) ov[e] = f2bf(ev[e] * inv);
  *(us8*)(row + t * 8) = ov;
}

// ---------------------------------------------------------------------------
// Kernel 4: out(f32) = probs(bf16) @ lv  using lvt[b][o][m] (B^T layout), K=2048.
// ---------------------------------------------------------------------------
__global__ __launch_bounds__(256) void gemm_pv(const u16* __restrict__ probs,
                                               const u16* __restrict__ lvt,
                                               float* __restrict__ out) {
  const int z = blockIdx.z;
  const u16* A = probs + (size_t)z * 2048 * 2048;
  const u16* Bt = lvt + (size_t)z * 1024 * 2048;
  float* C = out + (size_t)z * 2048 * 1024;
  const int br = blockIdx.y, bc = blockIdx.x;
  const int tid = threadIdx.x, w = tid >> 6;
  const int l = tid & 63, fr = l & 15, fq = l >> 4;
  const int wm = w >> 1, wn = w & 1;

  __shared__ __align__(16) u16 Ab[128 * 32];
  __shared__ __align__(16) u16 Bb[128 * 32];

  f32x4 acc[4][4] = {};

  for (int k0 = 0; k0 < 2048; k0 += 32) {
#pragma unroll
    for (int i = 0; i < 2; ++i) {
      int li = i * 256 + tid;
      int row = li >> 2, seg = li & 3;
      gld16(A + (size_t)(br * 128 + row) * 2048 + k0 + seg * 8,
            Ab + (size_t)(i * 256 + w * 64) * 8);
      gld16(Bt + (size_t)(bc * 128 + row) * 2048 + k0 + seg * 8,
            Bb + (size_t)(i * 256 + w * 64) * 8);
    }
    __syncthreads();
    bfrag a[4], b[4];
#pragma unroll
    for (int m = 0; m < 4; ++m)
      a[m] = *(const bfrag*)(Ab + (wm * 64 + m * 16 + fr) * 32 + fq * 8);
#pragma unroll
    for (int n = 0; n < 4; ++n)
      b[n] = *(const bfrag*)(Bb + (wn * 64 + n * 16 + fr) * 32 + fq * 8);
#pragma unroll
    for (int m = 0; m < 4; ++m)
#pragma unroll
      for (int n = 0; n < 4; ++n)
        acc[m][n] = __builtin_amdgcn_mfma_f32_16x16x32_bf16(a[m], b[n], acc[m][n], 0, 0, 0);
    __syncthreads();
  }

#pragma unroll
  for (int m = 0; m < 4; ++m) {
    int r0 = br * 128 + wm * 64 + m * 16 + fq * 4;
#pragma unroll
    for (int n = 0; n < 4; ++n) {
      int c = bc * 128 + wn * 64 + n * 16 + fr;
      f32x4 vv = acc[m][n];
#pragma unroll
      for (int j = 0; j < 4; ++j)
        C[(size_t)(r0 + j) * 1024 + c] = vv[j];
    }
  }
}

// ---------------------------------------------------------------------------
extern "C" void kernel_launch(void* const* d_in, const int* in_sizes, int n_in,
                              void* d_out, int out_size, void* d_ws, size_t ws_size,
                              hipStream_t stream) {
  const float* q   = (const float*)d_in[0];
  const float* k   = (const float*)d_in[1];
  const float* v   = (const float*)d_in[2];
  const int*   seq = (const int*)d_in[3];
  const float* Wq  = (const float*)d_in[4];
  const float* bq  = (const float*)d_in[5];
  const float* Wk  = (const float*)d_in[6];
  const float* bk  = (const float*)d_in[7];
  const float* Wv  = (const float*)d_in[8];
  const float* bv  = (const float*)d_in[9];
  float* out = (float*)d_out;

  // workspace layout (bf16 elements)
  u16* ws = (u16*)d_ws;
  u16* wtq = ws;
  u16* wtk = wtq + (size_t)1024 * 1024;
  u16* wtv = wtk + (size_t)1024 * 1024;
  u16* lq  = wtv + (size_t)1024 * 1024;
  u16* lk  = lq + (size_t)16384 * 1024;
  u16* lvt = lk + (size_t)16384 * 1024;
  u16* probs = lvt + (size_t)16384 * 1024;
  // total = 3*2MB + 3*32MB + 128MB = ~166MB

  transpose_w<<<dim3(16, 16, 3), 256, 0, stream>>>(Wq, Wk, Wv, wtq, wtk, wtv);
  gemm_proj<false><<<dim3(8, 128), 256, 0, stream>>>(q, wtq, bq, lq);
  gemm_proj<false><<<dim3(8, 128), 256, 0, stream>>>(k, wtk, bk, lk);
  gemm_proj<true><<<dim3(8, 128), 256, 0, stream>>>(v, wtv, bv, lvt);
  gemm_scores<<<dim3(16, 16, 8), 256, 0, stream>>>(lq, lk, probs);
  softmax_mask<<<dim3(16384), 256, 0, stream>>>(probs, seq);
  gemm_pv<<<dim3(8, 16, 8), 256, 0, stream>>>(probs, lvt, out);
}

// Round 2
// 346.971 us; speedup vs baseline: 1.6031x; 1.6031x over previous
//
#include <hip/hip_runtime.h>
#include <hip/hip_bf16.h>

typedef unsigned short u16;
typedef __attribute__((ext_vector_type(8))) short bfrag;   // 8 bf16 = 4 VGPR (MFMA A/B frag)
typedef __attribute__((ext_vector_type(4))) float f32x4;   // MFMA C/D frag
typedef __attribute__((ext_vector_type(8))) unsigned short us8;
typedef __attribute__((ext_vector_type(4))) unsigned short us4;

__device__ __forceinline__ u16 f2bf(float f) {
  union { float f; unsigned int u; } x; x.f = f;
  unsigned int r = x.u + 0x7fffu + ((x.u >> 16) & 1u);
  return (u16)(r >> 16);
}
__device__ __forceinline__ float bf2f(u16 u) {
  union { unsigned int u; float f; } x; x.u = ((unsigned int)u) << 16;
  return x.f;
}

__device__ __forceinline__ void gld16(const void* g, void* l) {
  __builtin_amdgcn_global_load_lds((const __attribute__((address_space(1))) void*)g,
                                   (__attribute__((address_space(3))) void*)l, 16, 0, 0);
}

// ---------------------------------------------------------------------------
// Kernel 0: transpose + convert weights: W[k][n] f32 (1024x1024) -> Wt[n][k] bf16
// ---------------------------------------------------------------------------
__global__ __launch_bounds__(256) void transpose_w(const float* __restrict__ W0,
                                                   const float* __restrict__ W1,
                                                   const float* __restrict__ W2,
                                                   u16* __restrict__ T0,
                                                   u16* __restrict__ T1,
                                                   u16* __restrict__ T2) {
  const float* W = (blockIdx.z == 0) ? W0 : ((blockIdx.z == 1) ? W1 : W2);
  u16* T = (blockIdx.z == 0) ? T0 : ((blockIdx.z == 1) ? T1 : T2);
  __shared__ u16 tile[64][72];
  const int t = threadIdx.x;
  const int rr = t >> 4;
  const int cc = (t & 15) * 4;
  const int kbase = blockIdx.y * 64, nbase = blockIdx.x * 64;
#pragma unroll
  for (int j = 0; j < 4; ++j) {
    int kl = rr + j * 16;
    float4 v = *(const float4*)(W + (size_t)(kbase + kl) * 1024 + nbase + cc);
    tile[kl][cc + 0] = f2bf(v.x);
    tile[kl][cc + 1] = f2bf(v.y);
    tile[kl][cc + 2] = f2bf(v.z);
    tile[kl][cc + 3] = f2bf(v.w);
  }
  __syncthreads();
#pragma unroll
  for (int j = 0; j < 4; ++j) {
    int nl = rr + j * 16;
    us4 o;
    o[0] = tile[cc + 0][nl];
    o[1] = tile[cc + 1][nl];
    o[2] = tile[cc + 2][nl];
    o[3] = tile[cc + 3][nl];
    *(us4*)(T + (size_t)(nbase + nl) * 1024 + kbase + cc) = o;
  }
}

// ---------------------------------------------------------------------------
// Kernel 1: f32 -> bf16 convert (vectorized, grid-stride)
// ---------------------------------------------------------------------------
__global__ __launch_bounds__(256) void cvt_bf16(const float* __restrict__ src,
                                                u16* __restrict__ dst, int n8) {
  int i = blockIdx.x * blockDim.x + threadIdx.x;
  const int stride = gridDim.x * blockDim.x;
  for (; i < n8; i += stride) {
    const float4* p = (const float4*)(src + (size_t)i * 8);
    float4 v0 = p[0], v1 = p[1];
    us8 o;
    o[0] = f2bf(v0.x); o[1] = f2bf(v0.y); o[2] = f2bf(v0.z); o[3] = f2bf(v0.w);
    o[4] = f2bf(v1.x); o[5] = f2bf(v1.y); o[6] = f2bf(v1.z); o[7] = f2bf(v1.w);
    *(us8*)(dst + (size_t)i * 8) = o;
  }
}

// ---------------------------------------------------------------------------
// Kernel 2: 256x256-tile BT GEMM, BK=64, 512 threads (8 waves, 2M x 4N),
//   LDS 128 KiB double-buffered, XOR-swizzled staging (pre-swizzled global
//   source + swizzled ds_read), phase-split MFMA with raw barriers + setprio,
//   one vmcnt(0) drain per K-tile covered by 4 compute phases.
// C = A[M][K](bf16) x B[N][K]^T(bf16).
// OUT: 0 = bf16 + bias (ldc) | 1 = bf16 * 1/32 | 2 = lvt-transposed + bias |
//      3 = f32
// ---------------------------------------------------------------------------
template <int OUT>
__global__ __launch_bounds__(512, 2) void gemm256(const u16* __restrict__ gA,
                                                  const u16* __restrict__ gB,
                                                  const float* __restrict__ bias,
                                                  void* __restrict__ outp,
                                                  int K, int ldc,
                                                  size_t aStride, size_t bStride,
                                                  size_t cStride) {
  __shared__ u16 lds[65536];   // A: [0,32768) (2 bufs), B: [32768,65536)
  const int tid = threadIdx.x;
  const int z = blockIdx.z;
  const u16* A = gA + (size_t)z * aStride;
  const u16* B = gB + (size_t)z * bStride;
  const int brow = blockIdx.y * 256, bcol = blockIdx.x * 256;

  const int wv = tid >> 6, l = tid & 63;
  const int wm = wv >> 2, wn = wv & 3;
  const int fr = l & 15, fq = l >> 4;
  const int g0 = (fq ^ (fr & 7)) * 8;          // u16 offset of kk=0 granule
  const int g1 = ((4 + fq) ^ (fr & 7)) * 8;    // kk=1

  // staging: thread covers granule (c*512 + tid); row = c*64 + (tid>>3),
  // physical granule = tid&7, logical (global) granule = (tid&7) ^ (row&7)
  const int srow = tid >> 3;
  const int sg = (tid & 7) ^ (srow & 7);
  const u16* aS = A + (size_t)(brow + srow) * K + sg * 8;
  const u16* bS = B + (size_t)(bcol + srow) * K + sg * 8;
  u16* const dA = lds + (tid >> 6) * 512;            // wave-uniform LDS base
  u16* const dB = lds + 32768 + (tid >> 6) * 512;

  f32x4 acc[8][4] = {};
  const int NT = K >> 6;

  // prologue: stage tile 0 into buf 0
#pragma unroll
  for (int c = 0; c < 4; ++c) gld16(aS + (size_t)c * 64 * K, dA + c * 4096);
#pragma unroll
  for (int c = 0; c < 4; ++c) gld16(bS + (size_t)c * 64 * K, dB + c * 4096);
  asm volatile("s_waitcnt vmcnt(0)" ::: "memory");
  __builtin_amdgcn_s_barrier();

  for (int s = 0; s < NT; ++s) {
    const int cur = s & 1;
    const u16* At = lds + cur * 16384;
    const u16* Bt = lds + 32768 + cur * 16384;

    // issue next tile's staging first (drain at tile end is covered by 4 phases)
    if (s + 1 < NT) {
      const int nb = cur ^ 1;
      const size_t ko = (size_t)(s + 1) * 64;
#pragma unroll
      for (int c = 0; c < 4; ++c)
        gld16(aS + ko + (size_t)c * 64 * K, dA + nb * 16384 + c * 4096);
#pragma unroll
      for (int c = 0; c < 4; ++c)
        gld16(bS + ko + (size_t)c * 64 * K, dB + nb * 16384 + c * 4096);
    }

    bfrag a[4][2], b[2][2][2];
    // ---- phase 0: read A(mh=0) + B(nh=0), MFMA quadrant (0,0)
#pragma unroll
    for (int m = 0; m < 4; ++m) {
      const u16* p = At + (wm * 128 + m * 16 + fr) * 64;
      a[m][0] = *(const bfrag*)(p + g0);
      a[m][1] = *(const bfrag*)(p + g1);
    }
#pragma unroll
    for (int n = 0; n < 2; ++n) {
      const u16* p = Bt + (wn * 64 + n * 16 + fr) * 64;
      b[0][n][0] = *(const bfrag*)(p + g0);
      b[0][n][1] = *(const bfrag*)(p + g1);
    }
    __builtin_amdgcn_s_barrier();
    __builtin_amdgcn_s_setprio(1);
#pragma unroll
    for (int n = 0; n < 2; ++n)
#pragma unroll
      for (int m = 0; m < 4; ++m) {
        acc[m][n] = __builtin_amdgcn_mfma_f32_16x16x32_bf16(a[m][0], b[0][n][0], acc[m][n], 0, 0, 0);
        acc[m][n] = __builtin_amdgcn_mfma_f32_16x16x32_bf16(a[m][1], b[0][n][1], acc[m][n], 0, 0, 0);
      }
    __builtin_amdgcn_s_setprio(0);
    __builtin_amdgcn_s_barrier();

    // ---- phase 1: read B(nh=1), MFMA quadrant (0,1)
#pragma unroll
    for (int n = 0; n < 2; ++n) {
      const u16* p = Bt + (wn * 64 + 32 + n * 16 + fr) * 64;
      b[1][n][0] = *(const bfrag*)(p + g0);
      b[1][n][1] = *(const bfrag*)(p + g1);
    }
    __builtin_amdgcn_s_barrier();
    __builtin_amdgcn_s_setprio(1);
#pragma unroll
    for (int n = 0; n < 2; ++n)
#pragma unroll
      for (int m = 0; m < 4; ++m) {
        acc[m][2 + n] = __builtin_amdgcn_mfma_f32_16x16x32_bf16(a[m][0], b[1][n][0], acc[m][2 + n], 0, 0, 0);
        acc[m][2 + n] = __builtin_amdgcn_mfma_f32_16x16x32_bf16(a[m][1], b[1][n][1], acc[m][2 + n], 0, 0, 0);
      }
    __builtin_amdgcn_s_setprio(0);
    __builtin_amdgcn_s_barrier();

    // ---- phase 2: read A(mh=1), MFMA quadrant (1,0)
#pragma unroll
    for (int m = 0; m < 4; ++m) {
      const u16* p = At + (wm * 128 + 64 + m * 16 + fr) * 64;
      a[m][0] = *(const bfrag*)(p + g0);
      a[m][1] = *(const bfrag*)(p + g1);
    }
    __builtin_amdgcn_s_barrier();
    __builtin_amdgcn_s_setprio(1);
#pragma unroll
    for (int n = 0; n < 2; ++n)
#pragma unroll
      for (int m = 0; m < 4; ++m) {
        acc[4 + m][n] = __builtin_amdgcn_mfma_f32_16x16x32_bf16(a[m][0], b[0][n][0], acc[4 + m][n], 0, 0, 0);
        acc[4 + m][n] = __builtin_amdgcn_mfma_f32_16x16x32_bf16(a[m][1], b[0][n][1], acc[4 + m][n], 0, 0, 0);
      }
    __builtin_amdgcn_s_setprio(0);
    __builtin_amdgcn_s_barrier();

    // ---- phase 3: MFMA quadrant (1,1) (no new reads)
    __builtin_amdgcn_s_setprio(1);
#pragma unroll
    for (int n = 0; n < 2; ++n)
#pragma unroll
      for (int m = 0; m < 4; ++m) {
        acc[4 + m][2 + n] = __builtin_amdgcn_mfma_f32_16x16x32_bf16(a[m][0], b[1][n][0], acc[4 + m][2 + n], 0, 0, 0);
        acc[4 + m][2 + n] = __builtin_amdgcn_mfma_f32_16x16x32_bf16(a[m][1], b[1][n][1], acc[4 + m][2 + n], 0, 0, 0);
      }
    __builtin_amdgcn_s_setprio(0);

    // tile transition: next tile's stage must have landed; everyone done reading
    asm volatile("s_waitcnt vmcnt(0)" ::: "memory");
    __builtin_amdgcn_s_barrier();
  }

  // epilogue
#pragma unroll
  for (int mg = 0; mg < 8; ++mg) {
    const int r0 = brow + wm * 128 + mg * 16 + fq * 4;
#pragma unroll
    for (int n = 0; n < 4; ++n) {
      const int c = bcol + wn * 64 + n * 16 + fr;
      f32x4 vv = acc[mg][n];
      if constexpr (OUT == 0) {
        float bb = bias[c];
        u16* C = (u16*)outp;
#pragma unroll
        for (int j = 0; j < 4; ++j) C[(size_t)(r0 + j) * ldc + c] = f2bf(vv[j] + bb);
      } else if constexpr (OUT == 1) {
        u16* C = (u16*)outp + (size_t)z * cStride;
#pragma unroll
        for (int j = 0; j < 4; ++j) C[(size_t)(r0 + j) * ldc + c] = f2bf(vv[j] * 0.03125f);
      } else if constexpr (OUT == 2) {
        float bb = bias[c];
        const int bz = r0 >> 11, mm = r0 & 2047;
        us4 o;
#pragma unroll
        for (int j = 0; j < 4; ++j) o[j] = f2bf(vv[j] + bb);
        *(us4*)((u16*)outp + ((size_t)bz * 1024 + c) * 2048 + mm) = o;
      } else {
        float* C = (float*)outp + (size_t)z * cStride;
#pragma unroll
        for (int j = 0; j < 4; ++j) C[(size_t)(r0 + j) * ldc + c] = vv[j];
      }
    }
  }
}

// ---------------------------------------------------------------------------
// Kernel 3: masked softmax over m, in place on probs (bf16). One block per row.
// ---------------------------------------------------------------------------
__global__ __launch_bounds__(256) void softmax_mask(u16* __restrict__ probs,
                                                    const int* __restrict__ seq) {
  const int bid = blockIdx.x;
  const int b = bid >> 11, n = bid & 2047;
  const int len = seq[b];
  u16* row = probs + ((size_t)b * 2048 + n) * 2048;
  const int t = threadIdx.x;
  const int w = t >> 6, l = t & 63;

  us8 sv = *(const us8*)(row + t * 8);
  float vals[8];
  float vmax = -1e30f;
#pragma unroll
  for (int e = 0; e < 8; ++e) {
    int m = t * 8 + e;
    float x = bf2f(sv[e]);
    vals[e] = (m < len) ? x : -1e30f;
    vmax = fmaxf(vmax, vals[e]);
  }
#pragma unroll
  for (int o = 32; o > 0; o >>= 1) vmax = fmaxf(vmax, __shfl_xor(vmax, o, 64));
  __shared__ float sm[4], ss[4];
  if (l == 0) sm[w] = vmax;
  __syncthreads();
  vmax = fmaxf(fmaxf(sm[0], sm[1]), fmaxf(sm[2], sm[3]));

  float ev[8];
  float sum = 0.f;
#pragma unroll
  for (int e = 0; e < 8; ++e) {
    int m = t * 8 + e;
    float p = (m < len) ? __expf(vals[e] - vmax) : 0.f;
    ev[e] = p;
    sum += p;
  }
#pragma unroll
  for (int o = 32; o > 0; o >>= 1) sum += __shfl_xor(sum, o, 64);
  if (l == 0) ss[w] = sum;
  __syncthreads();
  sum = ss[0] + ss[1] + ss[2] + ss[3];
  float inv = 1.f / sum;
  us8 ov;
#pragma unroll
  for (int e = 0; e < 8; ++e) ov[e] = f2bf(ev[e] * inv);
  *(us8*)(row + t * 8) = ov;
}

// ---------------------------------------------------------------------------
extern "C" void kernel_launch(void* const* d_in, const int* in_sizes, int n_in,
                              void* d_out, int out_size, void* d_ws, size_t ws_size,
                              hipStream_t stream) {
  const float* q   = (const float*)d_in[0];
  const float* k   = (const float*)d_in[1];
  const float* v   = (const float*)d_in[2];
  const int*   seq = (const int*)d_in[3];
  const float* Wq  = (const float*)d_in[4];
  const float* bq  = (const float*)d_in[5];
  const float* Wk  = (const float*)d_in[6];
  const float* bk  = (const float*)d_in[7];
  const float* Wv  = (const float*)d_in[8];
  const float* bv  = (const float*)d_in[9];
  float* out = (float*)d_out;

  // workspace layout (u16 elements) — same 166 MB footprint as round 1:
  //   wt: 3 x 1M | lq/lk/lvt: 3 x 16M | probs: 33.5M (cvt buffer aliased in)
  u16* ws = (u16*)d_ws;
  u16* wtq = ws;
  u16* wtk = wtq + (size_t)1024 * 1024;
  u16* wtv = wtk + (size_t)1024 * 1024;
  u16* lq  = wtv + (size_t)1024 * 1024;
  u16* lk  = lq + (size_t)16384 * 1024;
  u16* lvt = lk + (size_t)16384 * 1024;
  u16* probs = lvt + (size_t)16384 * 1024;
  u16* cbuf = probs;   // 16M u16 convert buffer, dead before scores GEMM

  const size_t S21 = (size_t)2048 * 1024;   // per-batch stride, 2048x1024
  const size_t S22 = (size_t)2048 * 2048;   // per-batch stride, 2048x2048

  transpose_w<<<dim3(16, 16, 3), 256, 0, stream>>>(Wq, Wk, Wv, wtq, wtk, wtv);

  // Q projection
  cvt_bf16<<<dim3(2048), 256, 0, stream>>>(q, cbuf, 2097152);
  gemm256<0><<<dim3(4, 64, 1), 512, 0, stream>>>(cbuf, wtq, bq, lq, 1024, 1024, 0, 0, 0);
  // K projection
  cvt_bf16<<<dim3(2048), 256, 0, stream>>>(k, cbuf, 2097152);
  gemm256<0><<<dim3(4, 64, 1), 512, 0, stream>>>(cbuf, wtk, bk, lk, 1024, 1024, 0, 0, 0);
  // V projection -> transposed lvt[b][o][m]
  cvt_bf16<<<dim3(2048), 256, 0, stream>>>(v, cbuf, 2097152);
  gemm256<2><<<dim3(4, 64, 1), 512, 0, stream>>>(cbuf, wtv, bv, lvt, 1024, 1024, 0, 0, 0);

  // scores = lq @ lk^T / 32  (per batch)
  gemm256<1><<<dim3(8, 8, 8), 512, 0, stream>>>(lq, lk, nullptr, probs, 1024, 2048, S21, S21, S22);
  // masked softmax in place
  softmax_mask<<<dim3(16384), 256, 0, stream>>>(probs, seq);
  // out = probs @ lv  (per batch, lvt is B^T layout)
  gemm256<3><<<dim3(4, 8, 8), 512, 0, stream>>>(probs, lvt, nullptr, out, 2048, 1024, S22, S21, S21);
}

// Round 3
// 335.107 us; speedup vs baseline: 1.6599x; 1.0354x over previous
//
#include <hip/hip_runtime.h>
#include <hip/hip_bf16.h>

typedef unsigned short u16;
typedef __attribute__((ext_vector_type(8))) short bfrag;   // 8 bf16 = 4 VGPR (MFMA A/B frag)
typedef __attribute__((ext_vector_type(4))) float f32x4;   // MFMA C/D frag
typedef __attribute__((ext_vector_type(8))) unsigned short us8;
typedef __attribute__((ext_vector_type(4))) unsigned short us4;

__device__ __forceinline__ u16 f2bf(float f) {
  union { float f; unsigned int u; } x; x.f = f;
  unsigned int r = x.u + 0x7fffu + ((x.u >> 16) & 1u);
  return (u16)(r >> 16);
}
__device__ __forceinline__ float bf2f(u16 u) {
  union { unsigned int u; float f; } x; x.u = ((unsigned int)u) << 16;
  return x.f;
}

__device__ __forceinline__ void gld16(const void* g, void* l) {
  __builtin_amdgcn_global_load_lds((const __attribute__((address_space(1))) void*)g,
                                   (__attribute__((address_space(3))) void*)l, 16, 0, 0);
}

// ---------------------------------------------------------------------------
// Kernel 0: transpose + convert weights: W[k][n] f32 (1024x1024) -> Wt[n][k] bf16
// ---------------------------------------------------------------------------
__global__ __launch_bounds__(256) void transpose_w(const float* __restrict__ W0,
                                                   const float* __restrict__ W1,
                                                   const float* __restrict__ W2,
                                                   u16* __restrict__ T0,
                                                   u16* __restrict__ T1,
                                                   u16* __restrict__ T2) {
  const float* W = (blockIdx.z == 0) ? W0 : ((blockIdx.z == 1) ? W1 : W2);
  u16* T = (blockIdx.z == 0) ? T0 : ((blockIdx.z == 1) ? T1 : T2);
  __shared__ u16 tile[64][72];
  const int t = threadIdx.x;
  const int rr = t >> 4;
  const int cc = (t & 15) * 4;
  const int kbase = blockIdx.y * 64, nbase = blockIdx.x * 64;
#pragma unroll
  for (int j = 0; j < 4; ++j) {
    int kl = rr + j * 16;
    float4 v = *(const float4*)(W + (size_t)(kbase + kl) * 1024 + nbase + cc);
    tile[kl][cc + 0] = f2bf(v.x);
    tile[kl][cc + 1] = f2bf(v.y);
    tile[kl][cc + 2] = f2bf(v.z);
    tile[kl][cc + 3] = f2bf(v.w);
  }
  __syncthreads();
#pragma unroll
  for (int j = 0; j < 4; ++j) {
    int nl = rr + j * 16;
    us4 o;
    o[0] = tile[cc + 0][nl];
    o[1] = tile[cc + 1][nl];
    o[2] = tile[cc + 2][nl];
    o[3] = tile[cc + 3][nl];
    *(us4*)(T + (size_t)(nbase + nl) * 1024 + kbase + cc) = o;
  }
}

// ---------------------------------------------------------------------------
// Kernel 1: f32 -> bf16 convert (vectorized, grid-stride)
// ---------------------------------------------------------------------------
__global__ __launch_bounds__(256) void cvt_bf16(const float* __restrict__ src,
                                                u16* __restrict__ dst, int n8) {
  int i = blockIdx.x * blockDim.x + threadIdx.x;
  const int stride = gridDim.x * blockDim.x;
  for (; i < n8; i += stride) {
    const float4* p = (const float4*)(src + (size_t)i * 8);
    float4 v0 = p[0], v1 = p[1];
    us8 o;
    o[0] = f2bf(v0.x); o[1] = f2bf(v0.y); o[2] = f2bf(v0.z); o[3] = f2bf(v0.w);
    o[4] = f2bf(v1.x); o[5] = f2bf(v1.y); o[6] = f2bf(v1.z); o[7] = f2bf(v1.w);
    *(us8*)(dst + (size_t)i * 8) = o;
  }
}

// ---------------------------------------------------------------------------
// Kernel 2: 256x256-tile BT GEMM, BK=64, 512 threads (8 waves, 2M x 4N).
//   8-phase counted-vmcnt schedule (T3+T4): staging spread 2 quarter-units
//   per phase, ~1.5-tile lead, entry wait = vmcnt(6) (vmcnt(0) only on the
//   last tile). T2 XOR-swizzled staging (pre-swizzled global source),
//   T5 setprio around MFMA clusters, T1 bijective XCD blockIdx swizzle.
// C = A[M][K](bf16) x B[N][K]^T(bf16).
// OUT: 0 = bf16 + bias | 1 = bf16 * 1/32 | 2 = lvt-transposed + bias | 3 = f32
// ---------------------------------------------------------------------------
template <int OUT>
__global__ __launch_bounds__(512, 2) void gemm256(const u16* __restrict__ gA,
                                                  const u16* __restrict__ gB,
                                                  const float* __restrict__ bias,
                                                  void* __restrict__ outp,
                                                  int K, int ldc,
                                                  size_t aStride, size_t bStride,
                                                  size_t cStride) {
  __shared__ u16 lds[65536];   // A: [0,32768) (2 bufs), B: [32768,65536)
  const int tid = threadIdx.x;

  // ---- T1: bijective XCD swizzle of the flattened workgroup id (m204)
  const int gx = gridDim.x, gy = gridDim.y;
  const int nwg = gx * gy * gridDim.z;
  int orig = blockIdx.x + gx * (blockIdx.y + gy * blockIdx.z);
  {
    const int qq = nwg >> 3, rr2 = nwg & 7;
    const int xcd = orig & 7, idx = orig >> 3;
    orig = (xcd < rr2 ? xcd * (qq + 1) : rr2 * (qq + 1) + (xcd - rr2) * qq) + idx;
  }
  const int bx = orig % gx;
  const int tmp_ = orig / gx;
  const int by = tmp_ % gy, bz = tmp_ / gy;

  const u16* A = gA + (size_t)bz * aStride;
  const u16* B = gB + (size_t)bz * bStride;
  const int brow = by * 256, bcol = bx * 256;

  const int wv = tid >> 6, l = tid & 63;
  const int wm = wv >> 2, wn = wv & 3;
  const int fr = l & 15, fq = l >> 4;
  const int g0 = (fq ^ (fr & 7)) * 8;          // u16 offset of kk=0 granule
  const int g1 = ((4 + fq) ^ (fr & 7)) * 8;    // kk=1

  // staging: unit = 64-row quarter (8 KB), 1 gld16/thread.
  // row = srow (+64c), physical granule = tid&7, logical = (tid&7)^(row&7)
  const int srow = tid >> 3;
  const int sg = (tid & 7) ^ (srow & 7);
  const u16* aS = A + (size_t)(brow + srow) * K + sg * 8;
  const u16* bS = B + (size_t)(bcol + srow) * K + sg * 8;
  u16* const dA = lds + wv * 512;            // wave-uniform LDS base (u16)
  u16* const dB = lds + 32768 + wv * 512;

  f32x4 acc[8][4] = {};
  const int NT = K >> 6;

  auto stA = [&](int tile, int c, int buf) {
    gld16(aS + (size_t)tile * 64 + (size_t)c * 64 * K, dA + buf * 16384 + c * 4096);
  };
  auto stB = [&](int tile, int c, int buf) {
    gld16(bS + (size_t)tile * 64 + (size_t)c * 64 * K, dB + buf * 16384 + c * 4096);
  };

  // ---- prologue: all 8 units of tile 0 -> buf0; 6 units of tile 1 -> buf1
#pragma unroll
  for (int c = 0; c < 4; ++c) stA(0, c, 0);
#pragma unroll
  for (int c = 0; c < 4; ++c) stB(0, c, 0);
  if (NT > 1) {
    stA(1, 0, 1); stA(1, 2, 1);
    stB(1, 0, 1); stB(1, 1, 1); stB(1, 2, 1); stB(1, 3, 1);
  }

  for (int t = 0; t < NT; ++t) {
    const int cur = t & 1;
    const u16* At = lds + cur * 16384;
    const u16* Bt = lds + 32768 + cur * 16384;

    // entry: all of tile t landed when <=6 younger loads outstanding
    if (t + 1 < NT) asm volatile("s_waitcnt vmcnt(6)" ::: "memory");
    else            asm volatile("s_waitcnt vmcnt(0)" ::: "memory");
    __builtin_amdgcn_s_barrier();

    bfrag a[4][2], b[2][2][2];

    // ---- q0: read A(mh0) + B(nh0); stage A1,A3 of t+1 -> buf cur^1
#pragma unroll
    for (int m = 0; m < 4; ++m) {
      const u16* p = At + (wm * 128 + m * 16 + fr) * 64;
      a[m][0] = *(const bfrag*)(p + g0);
      a[m][1] = *(const bfrag*)(p + g1);
    }
#pragma unroll
    for (int n = 0; n < 2; ++n) {
      const u16* p = Bt + (wn * 64 + n * 16 + fr) * 64;
      b[0][n][0] = *(const bfrag*)(p + g0);
      b[0][n][1] = *(const bfrag*)(p + g1);
    }
    if (t + 1 < NT) { stA(t + 1, 1, cur ^ 1); stA(t + 1, 3, cur ^ 1); }
    __builtin_amdgcn_s_barrier();
    __builtin_amdgcn_s_setprio(1);
#pragma unroll
    for (int n = 0; n < 2; ++n)
#pragma unroll
      for (int m = 0; m < 4; ++m) {
        acc[m][n] = __builtin_amdgcn_mfma_f32_16x16x32_bf16(a[m][0], b[0][n][0], acc[m][n], 0, 0, 0);
        acc[m][n] = __builtin_amdgcn_mfma_f32_16x16x32_bf16(a[m][1], b[0][n][1], acc[m][n], 0, 0, 0);
      }
    __builtin_amdgcn_s_setprio(0);
    __builtin_amdgcn_s_barrier();

    // ---- q1: read B(nh1); stage A0,A2 of t+2 -> buf cur
#pragma unroll
    for (int n = 0; n < 2; ++n) {
      const u16* p = Bt + (wn * 64 + 32 + n * 16 + fr) * 64;
      b[1][n][0] = *(const bfrag*)(p + g0);
      b[1][n][1] = *(const bfrag*)(p + g1);
    }
    if (t + 2 < NT) { stA(t + 2, 0, cur); stA(t + 2, 2, cur); }
    __builtin_amdgcn_s_barrier();
    __builtin_amdgcn_s_setprio(1);
#pragma unroll
    for (int n = 0; n < 2; ++n)
#pragma unroll
      for (int m = 0; m < 4; ++m) {
        acc[m][2 + n] = __builtin_amdgcn_mfma_f32_16x16x32_bf16(a[m][0], b[1][n][0], acc[m][2 + n], 0, 0, 0);
        acc[m][2 + n] = __builtin_amdgcn_mfma_f32_16x16x32_bf16(a[m][1], b[1][n][1], acc[m][2 + n], 0, 0, 0);
      }
    __builtin_amdgcn_s_setprio(0);
    __builtin_amdgcn_s_barrier();

    // ---- q2: read A(mh1); stage B0,B1 of t+2 -> buf cur
#pragma unroll
    for (int m = 0; m < 4; ++m) {
      const u16* p = At + (wm * 128 + 64 + m * 16 + fr) * 64;
      a[m][0] = *(const bfrag*)(p + g0);
      a[m][1] = *(const bfrag*)(p + g1);
    }
    if (t + 2 < NT) { stB(t + 2, 0, cur); stB(t + 2, 1, cur); }
    __builtin_amdgcn_s_barrier();
    __builtin_amdgcn_s_setprio(1);
#pragma unroll
    for (int n = 0; n < 2; ++n)
#pragma unroll
      for (int m = 0; m < 4; ++m) {
        acc[4 + m][n] = __builtin_amdgcn_mfma_f32_16x16x32_bf16(a[m][0], b[0][n][0], acc[4 + m][n], 0, 0, 0);
        acc[4 + m][n] = __builtin_amdgcn_mfma_f32_16x16x32_bf16(a[m][1], b[0][n][1], acc[4 + m][n], 0, 0, 0);
      }
    __builtin_amdgcn_s_setprio(0);
    __builtin_amdgcn_s_barrier();

    // ---- q3: stage B2,B3 of t+2 -> buf cur; MFMA quadrant (1,1)
    if (t + 2 < NT) { stB(t + 2, 2, cur); stB(t + 2, 3, cur); }
    __builtin_amdgcn_s_setprio(1);
#pragma unroll
    for (int n = 0; n < 2; ++n)
#pragma unroll
      for (int m = 0; m < 4; ++m) {
        acc[4 + m][2 + n] = __builtin_amdgcn_mfma_f32_16x16x32_bf16(a[m][0], b[1][n][0], acc[4 + m][2 + n], 0, 0, 0);
        acc[4 + m][2 + n] = __builtin_amdgcn_mfma_f32_16x16x32_bf16(a[m][1], b[1][n][1], acc[4 + m][2 + n], 0, 0, 0);
      }
    __builtin_amdgcn_s_setprio(0);
    __builtin_amdgcn_s_barrier();
  }

  // epilogue
#pragma unroll
  for (int mg = 0; mg < 8; ++mg) {
    const int r0 = brow + wm * 128 + mg * 16 + fq * 4;
#pragma unroll
    for (int n = 0; n < 4; ++n) {
      const int c = bcol + wn * 64 + n * 16 + fr;
      f32x4 vv = acc[mg][n];
      if constexpr (OUT == 0) {
        float bb = bias[c];
        u16* C = (u16*)outp;
#pragma unroll
        for (int j = 0; j < 4; ++j) C[(size_t)(r0 + j) * ldc + c] = f2bf(vv[j] + bb);
      } else if constexpr (OUT == 1) {
        u16* C = (u16*)outp + (size_t)bz * cStride;
#pragma unroll
        for (int j = 0; j < 4; ++j) C[(size_t)(r0 + j) * ldc + c] = f2bf(vv[j] * 0.03125f);
      } else if constexpr (OUT == 2) {
        float bb = bias[c];
        const int bz2 = r0 >> 11, mm = r0 & 2047;
        us4 o;
#pragma unroll
        for (int j = 0; j < 4; ++j) o[j] = f2bf(vv[j] + bb);
        *(us4*)((u16*)outp + ((size_t)bz2 * 1024 + c) * 2048 + mm) = o;
      } else {
        float* C = (float*)outp + (size_t)bz * cStride;
#pragma unroll
        for (int j = 0; j < 4; ++j) C[(size_t)(r0 + j) * ldc + c] = vv[j];
      }
    }
  }
}

// ---------------------------------------------------------------------------
// Kernel 3: masked softmax over m, in place on probs (bf16). One block per row.
// ---------------------------------------------------------------------------
__global__ __launch_bounds__(256) void softmax_mask(u16* __restrict__ probs,
                                                    const int* __restrict__ seq) {
  const int bid = blockIdx.x;
  const int b = bid >> 11, n = bid & 2047;
  const int len = seq[b];
  u16* row = probs + ((size_t)b * 2048 + n) * 2048;
  const int t = threadIdx.x;
  const int w = t >> 6, l = t & 63;

  us8 sv = *(const us8*)(row + t * 8);
  float vals[8];
  float vmax = -1e30f;
#pragma unroll
  for (int e = 0; e < 8; ++e) {
    int m = t * 8 + e;
    float x = bf2f(sv[e]);
    vals[e] = (m < len) ? x : -1e30f;
    vmax = fmaxf(vmax, vals[e]);
  }
#pragma unroll
  for (int o = 32; o > 0; o >>= 1) vmax = fmaxf(vmax, __shfl_xor(vmax, o, 64));
  __shared__ float sm[4], ss[4];
  if (l == 0) sm[w] = vmax;
  __syncthreads();
  vmax = fmaxf(fmaxf(sm[0], sm[1]), fmaxf(sm[2], sm[3]));

  float ev[8];
  float sum = 0.f;
#pragma unroll
  for (int e = 0; e < 8; ++e) {
    int m = t * 8 + e;
    float p = (m < len) ? __expf(vals[e] - vmax) : 0.f;
    ev[e] = p;
    sum += p;
  }
#pragma unroll
  for (int o = 32; o > 0; o >>= 1) sum += __shfl_xor(sum, o, 64);
  if (l == 0) ss[w] = sum;
  __syncthreads();
  sum = ss[0] + ss[1] + ss[2] + ss[3];
  float inv = 1.f / sum;
  us8 ov;
#pragma unroll
  for (int e = 0; e < 8; ++e) ov[e] = f2bf(ev[e] * inv);
  *(us8*)(row + t * 8) = ov;
}

// ---------------------------------------------------------------------------
extern "C" void kernel_launch(void* const* d_in, const int* in_sizes, int n_in,
                              void* d_out, int out_size, void* d_ws, size_t ws_size,
                              hipStream_t stream) {
  const float* q   = (const float*)d_in[0];
  const float* k   = (const float*)d_in[1];
  const float* v   = (const float*)d_in[2];
  const int*   seq = (const int*)d_in[3];
  const float* Wq  = (const float*)d_in[4];
  const float* bq  = (const float*)d_in[5];
  const float* Wk  = (const float*)d_in[6];
  const float* bk  = (const float*)d_in[7];
  const float* Wv  = (const float*)d_in[8];
  const float* bv  = (const float*)d_in[9];
  float* out = (float*)d_out;

  // workspace layout (u16 elements) — ~166 MB:
  //   wt: 3 x 1M | lq/lk/lvt: 3 x 16M | probs: 33.5M (cvt buffer aliased in)
  u16* ws = (u16*)d_ws;
  u16* wtq = ws;
  u16* wtk = wtq + (size_t)1024 * 1024;
  u16* wtv = wtk + (size_t)1024 * 1024;
  u16* lq  = wtv + (size_t)1024 * 1024;
  u16* lk  = lq + (size_t)16384 * 1024;
  u16* lvt = lk + (size_t)16384 * 1024;
  u16* probs = lvt + (size_t)16384 * 1024;
  u16* cbuf = probs;   // 16M u16 convert buffer, dead before scores GEMM

  const size_t S21 = (size_t)2048 * 1024;   // per-batch stride, 2048x1024
  const size_t S22 = (size_t)2048 * 2048;   // per-batch stride, 2048x2048

  transpose_w<<<dim3(16, 16, 3), 256, 0, stream>>>(Wq, Wk, Wv, wtq, wtk, wtv);

  // Q projection
  cvt_bf16<<<dim3(2048), 256, 0, stream>>>(q, cbuf, 2097152);
  gemm256<0><<<dim3(4, 64, 1), 512, 0, stream>>>(cbuf, wtq, bq, lq, 1024, 1024, 0, 0, 0);
  // K projection
  cvt_bf16<<<dim3(2048), 256, 0, stream>>>(k, cbuf, 2097152);
  gemm256<0><<<dim3(4, 64, 1), 512, 0, stream>>>(cbuf, wtk, bk, lk, 1024, 1024, 0, 0, 0);
  // V projection -> transposed lvt[b][o][m]
  cvt_bf16<<<dim3(2048), 256, 0, stream>>>(v, cbuf, 2097152);
  gemm256<2><<<dim3(4, 64, 1), 512, 0, stream>>>(cbuf, wtv, bv, lvt, 1024, 1024, 0, 0, 0);

  // scores = lq @ lk^T / 32  (per batch)
  gemm256<1><<<dim3(8, 8, 8), 512, 0, stream>>>(lq, lk, nullptr, probs, 1024, 2048, S21, S21, S22);
  // masked softmax in place
  softmax_mask<<<dim3(16384), 256, 0, stream>>>(probs, seq);
  // out = probs @ lv  (per batch, lvt is B^T layout)
  gemm256<3><<<dim3(4, 8, 8), 512, 0, stream>>>(probs, lvt, nullptr, out, 2048, 1024, S22, S21, S21);
}

// Round 4
// 325.921 us; speedup vs baseline: 1.7067x; 1.0282x over previous
//
#include <hip/hip_runtime.h>
#include <hip/hip_bf16.h>

typedef unsigned short u16;
typedef __attribute__((ext_vector_type(8))) short bfrag;   // 8 bf16 = 4 VGPR (MFMA A/B frag)
typedef __attribute__((ext_vector_type(4))) float f32x4;   // MFMA C/D frag
typedef __attribute__((ext_vector_type(8))) unsigned short us8;
typedef __attribute__((ext_vector_type(4))) unsigned short us4;

__device__ __forceinline__ u16 f2bf(float f) {
  union { float f; unsigned int u; } x; x.f = f;
  unsigned int r = x.u + 0x7fffu + ((x.u >> 16) & 1u);
  return (u16)(r >> 16);
}
__device__ __forceinline__ float bf2f(u16 u) {
  union { unsigned int u; float f; } x; x.u = ((unsigned int)u) << 16;
  return x.f;
}

__device__ __forceinline__ void gld16(const void* g, void* l) {
  __builtin_amdgcn_global_load_lds((const __attribute__((address_space(1))) void*)g,
                                   (__attribute__((address_space(3))) void*)l, 16, 0, 0);
}

// ---------------------------------------------------------------------------
// Kernel 0: transpose + convert weights: W[k][n] f32 (1024x1024) -> Wt[n][k] bf16
// ---------------------------------------------------------------------------
__global__ __launch_bounds__(256) void transpose_w(const float* __restrict__ W0,
                                                   const float* __restrict__ W1,
                                                   const float* __restrict__ W2,
                                                   u16* __restrict__ T0,
                                                   u16* __restrict__ T1,
                                                   u16* __restrict__ T2) {
  const float* W = (blockIdx.z == 0) ? W0 : ((blockIdx.z == 1) ? W1 : W2);
  u16* T = (blockIdx.z == 0) ? T0 : ((blockIdx.z == 1) ? T1 : T2);
  __shared__ u16 tile[64][72];
  const int t = threadIdx.x;
  const int rr = t >> 4;
  const int cc = (t & 15) * 4;
  const int kbase = blockIdx.y * 64, nbase = blockIdx.x * 64;
#pragma unroll
  for (int j = 0; j < 4; ++j) {
    int kl = rr + j * 16;
    float4 v = *(const float4*)(W + (size_t)(kbase + kl) * 1024 + nbase + cc);
    tile[kl][cc + 0] = f2bf(v.x);
    tile[kl][cc + 1] = f2bf(v.y);
    tile[kl][cc + 2] = f2bf(v.z);
    tile[kl][cc + 3] = f2bf(v.w);
  }
  __syncthreads();
#pragma unroll
  for (int j = 0; j < 4; ++j) {
    int nl = rr + j * 16;
    us4 o;
    o[0] = tile[cc + 0][nl];
    o[1] = tile[cc + 1][nl];
    o[2] = tile[cc + 2][nl];
    o[3] = tile[cc + 3][nl];
    *(us4*)(T + (size_t)(nbase + nl) * 1024 + kbase + cc) = o;
  }
}

// ---------------------------------------------------------------------------
// Kernel 1: f32 -> bf16 convert (vectorized, grid-stride)
// ---------------------------------------------------------------------------
__global__ __launch_bounds__(256) void cvt_bf16(const float* __restrict__ src,
                                                u16* __restrict__ dst, int n8) {
  int i = blockIdx.x * blockDim.x + threadIdx.x;
  const int stride = gridDim.x * blockDim.x;
  for (; i < n8; i += stride) {
    const float4* p = (const float4*)(src + (size_t)i * 8);
    float4 v0 = p[0], v1 = p[1];
    us8 o;
    o[0] = f2bf(v0.x); o[1] = f2bf(v0.y); o[2] = f2bf(v0.z); o[3] = f2bf(v0.w);
    o[4] = f2bf(v1.x); o[5] = f2bf(v1.y); o[6] = f2bf(v1.z); o[7] = f2bf(v1.w);
    *(us8*)(dst + (size_t)i * 8) = o;
  }
}

// ---------------------------------------------------------------------------
// Kernel 2: 256x256-tile BT GEMM, BK=64, 512 threads (8 waves, 2M x 4N).
//   T2 XOR-swizzled staging, T3+T4 counted-vmcnt phases, T5 setprio,
//   T1 bijective XCD swizzle. Mask-aware:
//     OUT==1 (scores): block early-exits when bcol >= seq[bz]
//     OUT==3 (PV):     K-loop truncated at ceil(seq[bz]/64) tiles
// C = A[M][K](bf16) x B[N][K]^T(bf16).
// OUT: 0 = bf16 + bias | 1 = bf16 * 1/32 | 2 = lvt-transposed + bias | 3 = f32
// ---------------------------------------------------------------------------
template <int OUT>
__global__ __launch_bounds__(512, 2) void gemm256(const u16* __restrict__ gA,
                                                  const u16* __restrict__ gB,
                                                  const float* __restrict__ bias,
                                                  void* __restrict__ outp,
                                                  int K, int ldc,
                                                  size_t aStride, size_t bStride,
                                                  size_t cStride,
                                                  const int* __restrict__ seq) {
  __shared__ u16 lds[65536];   // A: [0,32768) (2 bufs), B: [32768,65536)
  const int tid = threadIdx.x;

  // ---- T1: bijective XCD swizzle of the flattened workgroup id (m204)
  const int gx = gridDim.x, gy = gridDim.y;
  const int nwg = gx * gy * gridDim.z;
  int orig = blockIdx.x + gx * (blockIdx.y + gy * blockIdx.z);
  {
    const int qq = nwg >> 3, rr2 = nwg & 7;
    const int xcd = orig & 7, idx = orig >> 3;
    orig = (xcd < rr2 ? xcd * (qq + 1) : rr2 * (qq + 1) + (xcd - rr2) * qq) + idx;
  }
  const int bx = orig % gx;
  const int tmp_ = orig / gx;
  const int by = tmp_ % gy, bz = tmp_ / gy;

  const u16* A = gA + (size_t)bz * aStride;
  const u16* B = gB + (size_t)bz * bStride;
  const int brow = by * 256, bcol = bx * 256;

  const int NT = K >> 6;
  int NTe = NT;
  if constexpr (OUT == 1) {
    if (bcol >= seq[bz]) return;   // masked-out score tile: never read downstream
  }
  if constexpr (OUT == 3) {
    const int len = seq[bz];
    const int nt2 = (len + 63) >> 6;  // probs are exactly 0 beyond ceil64(len)
    NTe = nt2 < NT ? nt2 : NT;
  }

  const int wv = tid >> 6, l = tid & 63;
  const int wm = wv >> 2, wn = wv & 3;
  const int fr = l & 15, fq = l >> 4;
  const int g0 = (fq ^ (fr & 7)) * 8;          // u16 offset of kk=0 granule
  const int g1 = ((4 + fq) ^ (fr & 7)) * 8;    // kk=1

  // staging: unit = 64-row quarter (8 KB), 1 gld16/thread.
  const int srow = tid >> 3;
  const int sg = (tid & 7) ^ (srow & 7);
  const u16* aS = A + (size_t)(brow + srow) * K + sg * 8;
  const u16* bS = B + (size_t)(bcol + srow) * K + sg * 8;
  u16* const dA = lds + wv * 512;            // wave-uniform LDS base (u16)
  u16* const dB = lds + 32768 + wv * 512;

  f32x4 acc[8][4] = {};

  auto stA = [&](int tile, int c, int buf) {
    gld16(aS + (size_t)tile * 64 + (size_t)c * 64 * K, dA + buf * 16384 + c * 4096);
  };
  auto stB = [&](int tile, int c, int buf) {
    gld16(bS + (size_t)tile * 64 + (size_t)c * 64 * K, dB + buf * 16384 + c * 4096);
  };

  // ---- prologue: all 8 units of tile 0 -> buf0; 6 units of tile 1 -> buf1
#pragma unroll
  for (int c = 0; c < 4; ++c) stA(0, c, 0);
#pragma unroll
  for (int c = 0; c < 4; ++c) stB(0, c, 0);
  if (NTe > 1) {
    stA(1, 0, 1); stA(1, 2, 1);
    stB(1, 0, 1); stB(1, 1, 1); stB(1, 2, 1); stB(1, 3, 1);
  }

  for (int t = 0; t < NTe; ++t) {
    const int cur = t & 1;
    const u16* At = lds + cur * 16384;
    const u16* Bt = lds + 32768 + cur * 16384;

    // entry: all of tile t landed when <=6 younger loads outstanding
    if (t + 1 < NTe) asm volatile("s_waitcnt vmcnt(6)" ::: "memory");
    else             asm volatile("s_waitcnt vmcnt(0)" ::: "memory");
    __builtin_amdgcn_s_barrier();

    bfrag a[4][2], b[2][2][2];

    // ---- q0: read A(mh0) + B(nh0); stage A1,A3 of t+1 -> buf cur^1
#pragma unroll
    for (int m = 0; m < 4; ++m) {
      const u16* p = At + (wm * 128 + m * 16 + fr) * 64;
      a[m][0] = *(const bfrag*)(p + g0);
      a[m][1] = *(const bfrag*)(p + g1);
    }
#pragma unroll
    for (int n = 0; n < 2; ++n) {
      const u16* p = Bt + (wn * 64 + n * 16 + fr) * 64;
      b[0][n][0] = *(const bfrag*)(p + g0);
      b[0][n][1] = *(const bfrag*)(p + g1);
    }
    if (t + 1 < NTe) { stA(t + 1, 1, cur ^ 1); stA(t + 1, 3, cur ^ 1); }
    __builtin_amdgcn_s_barrier();
    asm volatile("s_waitcnt lgkmcnt(0)" ::: "memory");
    __builtin_amdgcn_sched_barrier(0);
    __builtin_amdgcn_s_setprio(1);
#pragma unroll
    for (int n = 0; n < 2; ++n)
#pragma unroll
      for (int m = 0; m < 4; ++m) {
        acc[m][n] = __builtin_amdgcn_mfma_f32_16x16x32_bf16(a[m][0], b[0][n][0], acc[m][n], 0, 0, 0);
        acc[m][n] = __builtin_amdgcn_mfma_f32_16x16x32_bf16(a[m][1], b[0][n][1], acc[m][n], 0, 0, 0);
      }
    __builtin_amdgcn_s_setprio(0);
    __builtin_amdgcn_s_barrier();

    // ---- q1: read B(nh1); stage A0,A2 of t+2 -> buf cur
#pragma unroll
    for (int n = 0; n < 2; ++n) {
      const u16* p = Bt + (wn * 64 + 32 + n * 16 + fr) * 64;
      b[1][n][0] = *(const bfrag*)(p + g0);
      b[1][n][1] = *(const bfrag*)(p + g1);
    }
    if (t + 2 < NTe) { stA(t + 2, 0, cur); stA(t + 2, 2, cur); }
    __builtin_amdgcn_s_barrier();
    asm volatile("s_waitcnt lgkmcnt(0)" ::: "memory");
    __builtin_amdgcn_sched_barrier(0);
    __builtin_amdgcn_s_setprio(1);
#pragma unroll
    for (int n = 0; n < 2; ++n)
#pragma unroll
      for (int m = 0; m < 4; ++m) {
        acc[m][2 + n] = __builtin_amdgcn_mfma_f32_16x16x32_bf16(a[m][0], b[1][n][0], acc[m][2 + n], 0, 0, 0);
        acc[m][2 + n] = __builtin_amdgcn_mfma_f32_16x16x32_bf16(a[m][1], b[1][n][1], acc[m][2 + n], 0, 0, 0);
      }
    __builtin_amdgcn_s_setprio(0);
    __builtin_amdgcn_s_barrier();

    // ---- q2: read A(mh1); stage B0,B1 of t+2 -> buf cur
#pragma unroll
    for (int m = 0; m < 4; ++m) {
      const u16* p = At + (wm * 128 + 64 + m * 16 + fr) * 64;
      a[m][0] = *(const bfrag*)(p + g0);
      a[m][1] = *(const bfrag*)(p + g1);
    }
    if (t + 2 < NTe) { stB(t + 2, 0, cur); stB(t + 2, 1, cur); }
    __builtin_amdgcn_s_barrier();
    asm volatile("s_waitcnt lgkmcnt(0)" ::: "memory");
    __builtin_amdgcn_sched_barrier(0);
    __builtin_amdgcn_s_setprio(1);
#pragma unroll
    for (int n = 0; n < 2; ++n)
#pragma unroll
      for (int m = 0; m < 4; ++m) {
        acc[4 + m][n] = __builtin_amdgcn_mfma_f32_16x16x32_bf16(a[m][0], b[0][n][0], acc[4 + m][n], 0, 0, 0);
        acc[4 + m][n] = __builtin_amdgcn_mfma_f32_16x16x32_bf16(a[m][1], b[0][n][1], acc[4 + m][n], 0, 0, 0);
      }
    __builtin_amdgcn_s_setprio(0);
    __builtin_amdgcn_s_barrier();

    // ---- q3: stage B2,B3 of t+2 -> buf cur; MFMA quadrant (1,1)
    if (t + 2 < NTe) { stB(t + 2, 2, cur); stB(t + 2, 3, cur); }
    __builtin_amdgcn_s_setprio(1);
#pragma unroll
    for (int n = 0; n < 2; ++n)
#pragma unroll
      for (int m = 0; m < 4; ++m) {
        acc[4 + m][2 + n] = __builtin_amdgcn_mfma_f32_16x16x32_bf16(a[m][0], b[1][n][0], acc[4 + m][2 + n], 0, 0, 0);
        acc[4 + m][2 + n] = __builtin_amdgcn_mfma_f32_16x16x32_bf16(a[m][1], b[1][n][1], acc[4 + m][2 + n], 0, 0, 0);
      }
    __builtin_amdgcn_s_setprio(0);
    // (no trailing barrier: next tile's entry vmcnt+barrier is the sync point)
  }

  // epilogue
#pragma unroll
  for (int mg = 0; mg < 8; ++mg) {
    const int r0 = brow + wm * 128 + mg * 16 + fq * 4;
#pragma unroll
    for (int n = 0; n < 4; ++n) {
      const int c = bcol + wn * 64 + n * 16 + fr;
      f32x4 vv = acc[mg][n];
      if constexpr (OUT == 0) {
        float bb = bias[c];
        u16* C = (u16*)outp;
#pragma unroll
        for (int j = 0; j < 4; ++j) C[(size_t)(r0 + j) * ldc + c] = f2bf(vv[j] + bb);
      } else if constexpr (OUT == 1) {
        u16* C = (u16*)outp + (size_t)bz * cStride;
#pragma unroll
        for (int j = 0; j < 4; ++j) C[(size_t)(r0 + j) * ldc + c] = f2bf(vv[j] * 0.03125f);
      } else if constexpr (OUT == 2) {
        float bb = bias[c];
        const int bz2 = r0 >> 11, mm = r0 & 2047;
        us4 o;
#pragma unroll
        for (int j = 0; j < 4; ++j) o[j] = f2bf(vv[j] + bb);
        *(us4*)((u16*)outp + ((size_t)bz2 * 1024 + c) * 2048 + mm) = o;
      } else {
        float* C = (float*)outp + (size_t)bz * cStride;
#pragma unroll
        for (int j = 0; j < 4; ++j) C[(size_t)(r0 + j) * ldc + c] = vv[j];
      }
    }
  }
}

// ---------------------------------------------------------------------------
// Kernel 3: masked softmax over m, in place on probs (bf16). One block per row.
//   Skips loads for m >= len and stores for m >= ceil64(len) (PV never reads
//   beyond ceil64(len); everything in [len, ceil64(len)) is written as 0).
// ---------------------------------------------------------------------------
__global__ __launch_bounds__(256) void softmax_mask(u16* __restrict__ probs,
                                                    const int* __restrict__ seq) {
  const int bid = blockIdx.x;
  const int b = bid >> 11, n = bid & 2047;
  const int len = seq[b];
  const int len64 = (len + 63) & ~63;
  u16* row = probs + ((size_t)b * 2048 + n) * 2048;
  const int t = threadIdx.x;
  const int w = t >> 6, l = t & 63;

  us8 sv = {};
  if (t * 8 < len) sv = *(const us8*)(row + t * 8);
  float vals[8];
  float vmax = -1e30f;
#pragma unroll
  for (int e = 0; e < 8; ++e) {
    int m = t * 8 + e;
    float x = bf2f(sv[e]);
    vals[e] = (m < len) ? x : -1e30f;
    vmax = fmaxf(vmax, vals[e]);
  }
#pragma unroll
  for (int o = 32; o > 0; o >>= 1) vmax = fmaxf(vmax, __shfl_xor(vmax, o, 64));
  __shared__ float sm[4], ss[4];
  if (l == 0) sm[w] = vmax;
  __syncthreads();
  vmax = fmaxf(fmaxf(sm[0], sm[1]), fmaxf(sm[2], sm[3]));

  float ev[8];
  float sum = 0.f;
#pragma unroll
  for (int e = 0; e < 8; ++e) {
    int m = t * 8 + e;
    float p = (m < len) ? __expf(vals[e] - vmax) : 0.f;
    ev[e] = p;
    sum += p;
  }
#pragma unroll
  for (int o = 32; o > 0; o >>= 1) sum += __shfl_xor(sum, o, 64);
  if (l == 0) ss[w] = sum;
  __syncthreads();
  sum = ss[0] + ss[1] + ss[2] + ss[3];
  float inv = 1.f / sum;
  if (t * 8 < len64) {
    us8 ov;
#pragma unroll
    for (int e = 0; e < 8; ++e) ov[e] = f2bf(ev[e] * inv);
    *(us8*)(row + t * 8) = ov;
  }
}

// ---------------------------------------------------------------------------
extern "C" void kernel_launch(void* const* d_in, const int* in_sizes, int n_in,
                              void* d_out, int out_size, void* d_ws, size_t ws_size,
                              hipStream_t stream) {
  const float* q   = (const float*)d_in[0];
  const float* k   = (const float*)d_in[1];
  const float* v   = (const float*)d_in[2];
  const int*   seq = (const int*)d_in[3];
  const float* Wq  = (const float*)d_in[4];
  const float* bq  = (const float*)d_in[5];
  const float* Wk  = (const float*)d_in[6];
  const float* bk  = (const float*)d_in[7];
  const float* Wv  = (const float*)d_in[8];
  const float* bv  = (const float*)d_in[9];
  float* out = (float*)d_out;

  // workspace layout (u16 elements) — ~166 MB:
  //   wt: 3 x 1M | lq/lk/lvt: 3 x 16M | probs: 33.5M (cvt buffer aliased in)
  u16* ws = (u16*)d_ws;
  u16* wtq = ws;
  u16* wtk = wtq + (size_t)1024 * 1024;
  u16* wtv = wtk + (size_t)1024 * 1024;
  u16* lq  = wtv + (size_t)1024 * 1024;
  u16* lk  = lq + (size_t)16384 * 1024;
  u16* lvt = lk + (size_t)16384 * 1024;
  u16* probs = lvt + (size_t)16384 * 1024;
  u16* cbuf = probs;   // 16M u16 convert buffer, dead before scores GEMM

  const size_t S21 = (size_t)2048 * 1024;   // per-batch stride, 2048x1024
  const size_t S22 = (size_t)2048 * 2048;   // per-batch stride, 2048x2048

  transpose_w<<<dim3(16, 16, 3), 256, 0, stream>>>(Wq, Wk, Wv, wtq, wtk, wtv);

  // Q projection
  cvt_bf16<<<dim3(2048), 256, 0, stream>>>(q, cbuf, 2097152);
  gemm256<0><<<dim3(4, 64, 1), 512, 0, stream>>>(cbuf, wtq, bq, lq, 1024, 1024, 0, 0, 0, nullptr);
  // K projection
  cvt_bf16<<<dim3(2048), 256, 0, stream>>>(k, cbuf, 2097152);
  gemm256<0><<<dim3(4, 64, 1), 512, 0, stream>>>(cbuf, wtk, bk, lk, 1024, 1024, 0, 0, 0, nullptr);
  // V projection -> transposed lvt[b][o][m]
  cvt_bf16<<<dim3(2048), 256, 0, stream>>>(v, cbuf, 2097152);
  gemm256<2><<<dim3(4, 64, 1), 512, 0, stream>>>(cbuf, wtv, bv, lvt, 1024, 1024, 0, 0, 0, nullptr);

  // scores = lq @ lk^T / 32  (per batch, masked tiles skipped)
  gemm256<1><<<dim3(8, 8, 8), 512, 0, stream>>>(lq, lk, nullptr, probs, 1024, 2048, S21, S21, S22, seq);
  // masked softmax in place
  softmax_mask<<<dim3(16384), 256, 0, stream>>>(probs, seq);
  // out = probs @ lv  (per batch, lvt is B^T layout, K truncated at ceil64(len))
  gemm256<3><<<dim3(4, 8, 8), 512, 0, stream>>>(probs, lvt, nullptr, out, 2048, 1024, S22, S21, S21, seq);
}

// Round 5
// 320.824 us; speedup vs baseline: 1.7338x; 1.0159x over previous
//
#include <hip/hip_runtime.h>
#include <hip/hip_bf16.h>

typedef unsigned short u16;
typedef __attribute__((ext_vector_type(8))) short bfrag;   // 8 bf16 = 4 VGPR (MFMA A/B frag)
typedef __attribute__((ext_vector_type(4))) float f32x4;   // MFMA C/D frag
typedef __attribute__((ext_vector_type(8))) unsigned short us8;
typedef __attribute__((ext_vector_type(4))) unsigned short us4;

__device__ __forceinline__ u16 f2bf(float f) {
  union { float f; unsigned int u; } x; x.f = f;
  unsigned int r = x.u + 0x7fffu + ((x.u >> 16) & 1u);
  return (u16)(r >> 16);
}
__device__ __forceinline__ float bf2f(u16 u) {
  union { unsigned int u; float f; } x; x.u = ((unsigned int)u) << 16;
  return x.f;
}

__device__ __forceinline__ void gld16(const void* g, void* l) {
  __builtin_amdgcn_global_load_lds((const __attribute__((address_space(1))) void*)g,
                                   (__attribute__((address_space(3))) void*)l, 16, 0, 0);
}

// ---------------------------------------------------------------------------
// Kernel 0: transpose + convert weights: W[k][n] f32 (1024x1024) -> Wt[n][k] bf16
// ---------------------------------------------------------------------------
__global__ __launch_bounds__(256) void transpose_w(const float* __restrict__ W0,
                                                   const float* __restrict__ W1,
                                                   const float* __restrict__ W2,
                                                   u16* __restrict__ T0,
                                                   u16* __restrict__ T1,
                                                   u16* __restrict__ T2) {
  const float* W = (blockIdx.z == 0) ? W0 : ((blockIdx.z == 1) ? W1 : W2);
  u16* T = (blockIdx.z == 0) ? T0 : ((blockIdx.z == 1) ? T1 : T2);
  __shared__ u16 tile[64][72];
  const int t = threadIdx.x;
  const int rr = t >> 4;
  const int cc = (t & 15) * 4;
  const int kbase = blockIdx.y * 64, nbase = blockIdx.x * 64;
#pragma unroll
  for (int j = 0; j < 4; ++j) {
    int kl = rr + j * 16;
    float4 v = *(const float4*)(W + (size_t)(kbase + kl) * 1024 + nbase + cc);
    tile[kl][cc + 0] = f2bf(v.x);
    tile[kl][cc + 1] = f2bf(v.y);
    tile[kl][cc + 2] = f2bf(v.z);
    tile[kl][cc + 3] = f2bf(v.w);
  }
  __syncthreads();
#pragma unroll
  for (int j = 0; j < 4; ++j) {
    int nl = rr + j * 16;
    us4 o;
    o[0] = tile[cc + 0][nl];
    o[1] = tile[cc + 1][nl];
    o[2] = tile[cc + 2][nl];
    o[3] = tile[cc + 3][nl];
    *(us4*)(T + (size_t)(nbase + nl) * 1024 + kbase + cc) = o;
  }
}

// ---------------------------------------------------------------------------
// Kernel 1: f32 -> bf16 convert (vectorized, grid-stride)
// ---------------------------------------------------------------------------
__global__ __launch_bounds__(256) void cvt_bf16(const float* __restrict__ src,
                                                u16* __restrict__ dst, int n8) {
  int i = blockIdx.x * blockDim.x + threadIdx.x;
  const int stride = gridDim.x * blockDim.x;
  for (; i < n8; i += stride) {
    const float4* p = (const float4*)(src + (size_t)i * 8);
    float4 v0 = p[0], v1 = p[1];
    us8 o;
    o[0] = f2bf(v0.x); o[1] = f2bf(v0.y); o[2] = f2bf(v0.z); o[3] = f2bf(v0.w);
    o[4] = f2bf(v1.x); o[5] = f2bf(v1.y); o[6] = f2bf(v1.z); o[7] = f2bf(v1.w);
    *(us8*)(dst + (size_t)i * 8) = o;
  }
}

// ---------------------------------------------------------------------------
// Kernel 2: 256x256-tile BT GEMM, BK=64, 512 threads (8 waves, 2M x 4N).
//   T2 XOR-swizzled staging, T3+T4 counted-vmcnt phases, T5 setprio.
//   Panel-sharing block mapping (replaces generic XCD swizzle): blocks
//   resident on one XCD (id&7 round-robin) share the A-panel so staged
//   A-bytes come from L2 instead of the L3->L2 pipe (delivery-bound fix).
//   Mask-aware: OUT==1 early-exits bcol>=len; OUT==3 truncates K at ceil64.
// C = A[M][K](bf16) x B[N][K]^T(bf16).
// OUT: 0 = bf16 + bias | 1 = bf16 * 1/32 | 2 = lvt-transposed + bias | 3 = f32
// ---------------------------------------------------------------------------
template <int OUT>
__global__ __launch_bounds__(512, 2) void gemm256(const u16* __restrict__ gA,
                                                  const u16* __restrict__ gB,
                                                  const float* __restrict__ bias,
                                                  void* __restrict__ outp,
                                                  int K, int ldc,
                                                  size_t aStride, size_t bStride,
                                                  size_t cStride,
                                                  const int* __restrict__ seq) {
  __shared__ u16 lds[65536];   // A: [0,32768) (2 bufs), B: [32768,65536)
  const int tid = threadIdx.x;

  // ---- panel-sharing mapping: groups of 8 consecutive ids (one per XCD
  //      slot-cycle) share (by,bz) and sweep bx. XCD = id&7 (round-robin).
  const int id = blockIdx.x + gridDim.x * (blockIdx.y + gridDim.y * blockIdx.z);
  int bx, by, bz;
  if constexpr (OUT == 0 || OUT == 2) {      // proj: grid (4, 64, 1)
    bx = (id >> 3) & 3; by = (id & 7) + 8 * (id >> 5); bz = 0;
  } else if constexpr (OUT == 1) {           // scores: grid (8, 8, 8)
    bx = (id >> 3) & 7; by = id & 7; bz = id >> 6;
  } else {                                   // PV: grid (4, 8, 8)
    bx = (id >> 3) & 3; by = id & 7; bz = id >> 5;
  }

  const u16* A = gA + (size_t)bz * aStride;
  const u16* B = gB + (size_t)bz * bStride;
  const int brow = by * 256, bcol = bx * 256;

  const int NT = K >> 6;
  int NTe = NT;
  if constexpr (OUT == 1) {
    if (bcol >= seq[bz]) return;   // masked-out score tile: never read downstream
  }
  if constexpr (OUT == 3) {
    const int len = seq[bz];
    const int nt2 = (len + 63) >> 6;  // probs are exactly 0 beyond ceil64(len)
    NTe = nt2 < NT ? nt2 : NT;
  }

  const int wv = tid >> 6, l = tid & 63;
  const int wm = wv >> 2, wn = wv & 3;
  const int fr = l & 15, fq = l >> 4;
  const int g0 = (fq ^ (fr & 7)) * 8;          // u16 offset of kk=0 granule
  const int g1 = ((4 + fq) ^ (fr & 7)) * 8;    // kk=1

  // staging: unit = 64-row quarter (8 KB), 1 gld16/thread.
  const int srow = tid >> 3;
  const int sg = (tid & 7) ^ (srow & 7);
  const u16* aS = A + (size_t)(brow + srow) * K + sg * 8;
  const u16* bS = B + (size_t)(bcol + srow) * K + sg * 8;
  u16* const dA = lds + wv * 512;            // wave-uniform LDS base (u16)
  u16* const dB = lds + 32768 + wv * 512;

  f32x4 acc[8][4] = {};

  auto stA = [&](int tile, int c, int buf) {
    gld16(aS + (size_t)tile * 64 + (size_t)c * 64 * K, dA + buf * 16384 + c * 4096);
  };
  auto stB = [&](int tile, int c, int buf) {
    gld16(bS + (size_t)tile * 64 + (size_t)c * 64 * K, dB + buf * 16384 + c * 4096);
  };

  // ---- prologue: all 8 units of tile 0 -> buf0; 6 units of tile 1 -> buf1
#pragma unroll
  for (int c = 0; c < 4; ++c) stA(0, c, 0);
#pragma unroll
  for (int c = 0; c < 4; ++c) stB(0, c, 0);
  if (NTe > 1) {
    stA(1, 0, 1); stA(1, 2, 1);
    stB(1, 0, 1); stB(1, 1, 1); stB(1, 2, 1); stB(1, 3, 1);
  }

  for (int t = 0; t < NTe; ++t) {
    const int cur = t & 1;
    const u16* At = lds + cur * 16384;
    const u16* Bt = lds + 32768 + cur * 16384;

    // entry: all of tile t landed when <=6 younger loads outstanding
    if (t + 1 < NTe) asm volatile("s_waitcnt vmcnt(6)" ::: "memory");
    else             asm volatile("s_waitcnt vmcnt(0)" ::: "memory");
    __builtin_amdgcn_s_barrier();

    bfrag a[4][2], b[2][2][2];

    // ---- q0: read A(mh0) + B(nh0); stage A1,A3 of t+1 -> buf cur^1
#pragma unroll
    for (int m = 0; m < 4; ++m) {
      const u16* p = At + (wm * 128 + m * 16 + fr) * 64;
      a[m][0] = *(const bfrag*)(p + g0);
      a[m][1] = *(const bfrag*)(p + g1);
    }
#pragma unroll
    for (int n = 0; n < 2; ++n) {
      const u16* p = Bt + (wn * 64 + n * 16 + fr) * 64;
      b[0][n][0] = *(const bfrag*)(p + g0);
      b[0][n][1] = *(const bfrag*)(p + g1);
    }
    if (t + 1 < NTe) { stA(t + 1, 1, cur ^ 1); stA(t + 1, 3, cur ^ 1); }
    __builtin_amdgcn_s_barrier();
    asm volatile("s_waitcnt lgkmcnt(0)" ::: "memory");
    __builtin_amdgcn_sched_barrier(0);
    __builtin_amdgcn_s_setprio(1);
#pragma unroll
    for (int n = 0; n < 2; ++n)
#pragma unroll
      for (int m = 0; m < 4; ++m) {
        acc[m][n] = __builtin_amdgcn_mfma_f32_16x16x32_bf16(a[m][0], b[0][n][0], acc[m][n], 0, 0, 0);
        acc[m][n] = __builtin_amdgcn_mfma_f32_16x16x32_bf16(a[m][1], b[0][n][1], acc[m][n], 0, 0, 0);
      }
    __builtin_amdgcn_s_setprio(0);
    __builtin_amdgcn_s_barrier();

    // ---- q1: read B(nh1); stage A0,A2 of t+2 -> buf cur
#pragma unroll
    for (int n = 0; n < 2; ++n) {
      const u16* p = Bt + (wn * 64 + 32 + n * 16 + fr) * 64;
      b[1][n][0] = *(const bfrag*)(p + g0);
      b[1][n][1] = *(const bfrag*)(p + g1);
    }
    if (t + 2 < NTe) { stA(t + 2, 0, cur); stA(t + 2, 2, cur); }
    __builtin_amdgcn_s_barrier();
    asm volatile("s_waitcnt lgkmcnt(0)" ::: "memory");
    __builtin_amdgcn_sched_barrier(0);
    __builtin_amdgcn_s_setprio(1);
#pragma unroll
    for (int n = 0; n < 2; ++n)
#pragma unroll
      for (int m = 0; m < 4; ++m) {
        acc[m][2 + n] = __builtin_amdgcn_mfma_f32_16x16x32_bf16(a[m][0], b[1][n][0], acc[m][2 + n], 0, 0, 0);
        acc[m][2 + n] = __builtin_amdgcn_mfma_f32_16x16x32_bf16(a[m][1], b[1][n][1], acc[m][2 + n], 0, 0, 0);
      }
    __builtin_amdgcn_s_setprio(0);
    __builtin_amdgcn_s_barrier();

    // ---- q2: read A(mh1); stage B0,B1 of t+2 -> buf cur
#pragma unroll
    for (int m = 0; m < 4; ++m) {
      const u16* p = At + (wm * 128 + 64 + m * 16 + fr) * 64;
      a[m][0] = *(const bfrag*)(p + g0);
      a[m][1] = *(const bfrag*)(p + g1);
    }
    if (t + 2 < NTe) { stB(t + 2, 0, cur); stB(t + 2, 1, cur); }
    __builtin_amdgcn_s_barrier();
    asm volatile("s_waitcnt lgkmcnt(0)" ::: "memory");
    __builtin_amdgcn_sched_barrier(0);
    __builtin_amdgcn_s_setprio(1);
#pragma unroll
    for (int n = 0; n < 2; ++n)
#pragma unroll
      for (int m = 0; m < 4; ++m) {
        acc[4 + m][n] = __builtin_amdgcn_mfma_f32_16x16x32_bf16(a[m][0], b[0][n][0], acc[4 + m][n], 0, 0, 0);
        acc[4 + m][n] = __builtin_amdgcn_mfma_f32_16x16x32_bf16(a[m][1], b[0][n][1], acc[4 + m][n], 0, 0, 0);
      }
    __builtin_amdgcn_s_setprio(0);
    __builtin_amdgcn_s_barrier();

    // ---- q3: stage B2,B3 of t+2 -> buf cur; MFMA quadrant (1,1)
    if (t + 2 < NTe) { stB(t + 2, 2, cur); stB(t + 2, 3, cur); }
    __builtin_amdgcn_s_setprio(1);
#pragma unroll
    for (int n = 0; n < 2; ++n)
#pragma unroll
      for (int m = 0; m < 4; ++m) {
        acc[4 + m][2 + n] = __builtin_amdgcn_mfma_f32_16x16x32_bf16(a[m][0], b[1][n][0], acc[4 + m][2 + n], 0, 0, 0);
        acc[4 + m][2 + n] = __builtin_amdgcn_mfma_f32_16x16x32_bf16(a[m][1], b[1][n][1], acc[4 + m][2 + n], 0, 0, 0);
      }
    __builtin_amdgcn_s_setprio(0);
    // (no trailing barrier: next tile's entry vmcnt+barrier is the sync point)
  }

  // epilogue
#pragma unroll
  for (int mg = 0; mg < 8; ++mg) {
    const int r0 = brow + wm * 128 + mg * 16 + fq * 4;
#pragma unroll
    for (int n = 0; n < 4; ++n) {
      const int c = bcol + wn * 64 + n * 16 + fr;
      f32x4 vv = acc[mg][n];
      if constexpr (OUT == 0) {
        float bb = bias[c];
        u16* C = (u16*)outp;
#pragma unroll
        for (int j = 0; j < 4; ++j) C[(size_t)(r0 + j) * ldc + c] = f2bf(vv[j] + bb);
      } else if constexpr (OUT == 1) {
        u16* C = (u16*)outp + (size_t)bz * cStride;
#pragma unroll
        for (int j = 0; j < 4; ++j) C[(size_t)(r0 + j) * ldc + c] = f2bf(vv[j] * 0.03125f);
      } else if constexpr (OUT == 2) {
        float bb = bias[c];
        const int bz2 = r0 >> 11, mm = r0 & 2047;
        us4 o;
#pragma unroll
        for (int j = 0; j < 4; ++j) o[j] = f2bf(vv[j] + bb);
        *(us4*)((u16*)outp + ((size_t)bz2 * 1024 + c) * 2048 + mm) = o;
      } else {
        float* C = (float*)outp + (size_t)bz * cStride;
#pragma unroll
        for (int j = 0; j < 4; ++j) C[(size_t)(r0 + j) * ldc + c] = vv[j];
      }
    }
  }
}

// ---------------------------------------------------------------------------
// Kernel 3: masked softmax over m, in place on probs (bf16). One block per row.
// ---------------------------------------------------------------------------
__global__ __launch_bounds__(256) void softmax_mask(u16* __restrict__ probs,
                                                    const int* __restrict__ seq) {
  const int bid = blockIdx.x;
  const int b = bid >> 11, n = bid & 2047;
  const int len = seq[b];
  const int len64 = (len + 63) & ~63;
  u16* row = probs + ((size_t)b * 2048 + n) * 2048;
  const int t = threadIdx.x;
  const int w = t >> 6, l = t & 63;

  us8 sv = {};
  if (t * 8 < len) sv = *(const us8*)(row + t * 8);
  float vals[8];
  float vmax = -1e30f;
#pragma unroll
  for (int e = 0; e < 8; ++e) {
    int m = t * 8 + e;
    float x = bf2f(sv[e]);
    vals[e] = (m < len) ? x : -1e30f;
    vmax = fmaxf(vmax, vals[e]);
  }
#pragma unroll
  for (int o = 32; o > 0; o >>= 1) vmax = fmaxf(vmax, __shfl_xor(vmax, o, 64));
  __shared__ float sm[4], ss[4];
  if (l == 0) sm[w] = vmax;
  __syncthreads();
  vmax = fmaxf(fmaxf(sm[0], sm[1]), fmaxf(sm[2], sm[3]));

  float ev[8];
  float sum = 0.f;
#pragma unroll
  for (int e = 0; e < 8; ++e) {
    int m = t * 8 + e;
    float p = (m < len) ? __expf(vals[e] - vmax) : 0.f;
    ev[e] = p;
    sum += p;
  }
#pragma unroll
  for (int o = 32; o > 0; o >>= 1) sum += __shfl_xor(sum, o, 64);
  if (l == 0) ss[w] = sum;
  __syncthreads();
  sum = ss[0] + ss[1] + ss[2] + ss[3];
  float inv = 1.f / sum;
  if (t * 8 < len64) {
    us8 ov;
#pragma unroll
    for (int e = 0; e < 8; ++e) ov[e] = f2bf(ev[e] * inv);
    *(us8*)(row + t * 8) = ov;
  }
}

// ---------------------------------------------------------------------------
extern "C" void kernel_launch(void* const* d_in, const int* in_sizes, int n_in,
                              void* d_out, int out_size, void* d_ws, size_t ws_size,
                              hipStream_t stream) {
  const float* q   = (const float*)d_in[0];
  const float* k   = (const float*)d_in[1];
  const float* v   = (const float*)d_in[2];
  const int*   seq = (const int*)d_in[3];
  const float* Wq  = (const float*)d_in[4];
  const float* bq  = (const float*)d_in[5];
  const float* Wk  = (const float*)d_in[6];
  const float* bk  = (const float*)d_in[7];
  const float* Wv  = (const float*)d_in[8];
  const float* bv  = (const float*)d_in[9];
  float* out = (float*)d_out;

  // workspace layout (u16 elements) — ~174 MB:
  //   wt: 3 x 1M | lq/lk/lvt: 3 x 16M | probs: 33.5M (cvt buffer aliased in)
  u16* ws = (u16*)d_ws;
  u16* wtq = ws;
  u16* wtk = wtq + (size_t)1024 * 1024;
  u16* wtv = wtk + (size_t)1024 * 1024;
  u16* lq  = wtv + (size_t)1024 * 1024;
  u16* lk  = lq + (size_t)16384 * 1024;
  u16* lvt = lk + (size_t)16384 * 1024;
  u16* probs = lvt + (size_t)16384 * 1024;
  u16* cbuf = probs;   // 16M u16 convert buffer, dead before scores GEMM

  const size_t S21 = (size_t)2048 * 1024;   // per-batch stride, 2048x1024
  const size_t S22 = (size_t)2048 * 2048;   // per-batch stride, 2048x2048

  transpose_w<<<dim3(16, 16, 3), 256, 0, stream>>>(Wq, Wk, Wv, wtq, wtk, wtv);

  // Q projection
  cvt_bf16<<<dim3(2048), 256, 0, stream>>>(q, cbuf, 2097152);
  gemm256<0><<<dim3(4, 64, 1), 512, 0, stream>>>(cbuf, wtq, bq, lq, 1024, 1024, 0, 0, 0, nullptr);
  // K projection
  cvt_bf16<<<dim3(2048), 256, 0, stream>>>(k, cbuf, 2097152);
  gemm256<0><<<dim3(4, 64, 1), 512, 0, stream>>>(cbuf, wtk, bk, lk, 1024, 1024, 0, 0, 0, nullptr);
  // V projection -> transposed lvt[b][o][m]
  cvt_bf16<<<dim3(2048), 256, 0, stream>>>(v, cbuf, 2097152);
  gemm256<2><<<dim3(4, 64, 1), 512, 0, stream>>>(cbuf, wtv, bv, lvt, 1024, 1024, 0, 0, 0, nullptr);

  // scores = lq @ lk^T / 32  (per batch, masked tiles skipped)
  gemm256<1><<<dim3(8, 8, 8), 512, 0, stream>>>(lq, lk, nullptr, probs, 1024, 2048, S21, S21, S22, seq);
  // masked softmax in place
  softmax_mask<<<dim3(16384), 256, 0, stream>>>(probs, seq);
  // out = probs @ lv  (per batch, lvt is B^T layout, K truncated at ceil64(len))
  gemm256<3><<<dim3(4, 8, 8), 512, 0, stream>>>(probs, lvt, nullptr, out, 2048, 1024, S22, S21, S21, seq);
}